// Round 15
// baseline (1819.246 us; speedup 1.0000x reference)
//
#include <hip/hip_runtime.h>

#define Lz 6
#define Bz 4
#define Tz 1024
#define Ez 1024
#define HQz 16
#define HKVz 4
#define Dz 64
#define EKVz 256
#define Vz 32000
#define FFz 4096
#define QKVz 1536   // E + EKV + EKV

typedef __attribute__((ext_vector_type(4))) float f32x4;
typedef __attribute__((ext_vector_type(8))) short short8;
typedef unsigned short ushort_t;

__device__ inline ushort_t f2b(float f) {
  union { float f; unsigned u; } x; x.f = f;
  unsigned r = x.u + 0x7fffu + ((x.u >> 16) & 1u);
  return (ushort_t)(r >> 16);
}
__device__ inline float b2f(ushort_t u) {
  union { unsigned u; float f; } x; x.u = ((unsigned)u) << 16;
  return x.f;
}
__device__ inline unsigned packbf(float lo, float hi) {
  return (unsigned)f2b(lo) | ((unsigned)f2b(hi) << 16);
}

__device__ inline void gload16(const void* g, void* l) {
  __builtin_amdgcn_global_load_lds(
      (const __attribute__((address_space(1))) void*)g,
      (__attribute__((address_space(3))) void*)l, 16, 0, 0);
}

// ================= 256x256 4-phase GEMM (measured 350us lm_head) =================
template<int BIAS, int GELU, int WF32>
__global__ __launch_bounds__(512, 2) void gemm_bt256(
    const ushort_t* __restrict__ A, const ushort_t* __restrict__ Bw,
    const float* __restrict__ bias,
    float* __restrict__ Cf, ushort_t* __restrict__ Cb,
    int M, int N, int K)
{
  __shared__ ushort_t sA[2][2][128 * 64];
  __shared__ ushort_t sB[2][2][128 * 64];
  const int tid = threadIdx.x;
  const int lane = tid & 63, wid = tid >> 6;
  const int wr = wid >> 2, wc = wid & 3;
  const int l15 = lane & 15, l4 = lane >> 4;

  const int gx = gridDim.x;
  const int nwg = gx * gridDim.y;
  const int orig = blockIdx.y * gx + blockIdx.x;
  const int qq = nwg >> 3, rr = nwg & 7;
  const int xcd = orig & 7, loc = orig >> 3;
  const int swz = (xcd < rr) ? (xcd * (qq + 1) + loc)
                             : (rr * (qq + 1) + (xcd - rr) * qq + loc);
  const int bm = swz % gx, bn = swz / gx;

  const int NT = K >> 6;

  auto stage = [&](const ushort_t* src, int row_base, int k0, ushort_t* dst) {
#pragma unroll
    for (int i = 0; i < 2; ++i) {
      int s = i * 512 + tid;
      int row = s >> 3, jp = s & 7;
      int jlog = jp ^ (row & 7);
      gload16(src + (size_t)(row_base + row) * K + k0 + jlog * 8, (char*)dst + s * 16);
    }
  };

  stage(A,  bm * 256,       0, &sA[0][0][0]);
  stage(A,  bm * 256 + 128, 0, &sA[0][1][0]);
  stage(Bw, bn * 256,       0, &sB[0][0][0]);
  stage(Bw, bn * 256 + 128, 0, &sB[0][1][0]);
  stage(A,  bm * 256,       64, &sA[1][0][0]);
  stage(A,  bm * 256 + 128, 64, &sA[1][1][0]);
  stage(Bw, bn * 256,       64, &sB[1][0][0]);
  stage(Bw, bn * 256 + 128, 64, &sB[1][1][0]);
  asm volatile("s_waitcnt vmcnt(8)" ::: "memory");
  __builtin_amdgcn_sched_barrier(0);
  __builtin_amdgcn_s_barrier();
  __builtin_amdgcn_sched_barrier(0);

  f32x4 acc[8][4] = {};
  const int axc = l15 & 7;

  for (int t = 0; t < NT; ++t) {
    const int b = t & 1;
    const ushort_t* pA = &sA[b][wr][0];
    const ushort_t* pB = &sB[b][wc >> 1][(wc & 1) * 64 * 64];
    short8 aF[8][2], bF[4][2];

#pragma unroll
    for (int mt = 0; mt < 4; ++mt)
#pragma unroll
      for (int ks = 0; ks < 2; ++ks)
        aF[mt][ks] = *(const short8*)&pA[(mt * 16 + l15) * 64 + (((ks << 2) + l4) ^ axc) * 8];
#pragma unroll
    for (int nt = 0; nt < 4; ++nt)
      bF[nt][0] = *(const short8*)&pB[(nt * 16 + l15) * 64 + (l4 ^ axc) * 8];
    __builtin_amdgcn_s_setprio(1);
#pragma unroll
    for (int mt = 0; mt < 4; ++mt)
#pragma unroll
      for (int nt = 0; nt < 4; ++nt)
        acc[mt][nt] = __builtin_amdgcn_mfma_f32_16x16x32_bf16(aF[mt][0], bF[nt][0], acc[mt][nt], 0, 0, 0);
    __builtin_amdgcn_s_setprio(0);

#pragma unroll
    for (int mt = 4; mt < 8; ++mt)
#pragma unroll
      for (int ks = 0; ks < 2; ++ks)
        aF[mt][ks] = *(const short8*)&pA[(mt * 16 + l15) * 64 + (((ks << 2) + l4) ^ axc) * 8];
#pragma unroll
    for (int nt = 0; nt < 4; ++nt)
      bF[nt][1] = *(const short8*)&pB[(nt * 16 + l15) * 64 + ((4 + l4) ^ axc) * 8];
    __builtin_amdgcn_s_setprio(1);
#pragma unroll
    for (int mt = 0; mt < 4; ++mt)
#pragma unroll
      for (int nt = 0; nt < 4; ++nt)
        acc[mt][nt] = __builtin_amdgcn_mfma_f32_16x16x32_bf16(aF[mt][1], bF[nt][1], acc[mt][nt], 0, 0, 0);
    __builtin_amdgcn_s_setprio(0);

    asm volatile("s_waitcnt lgkmcnt(0)" ::: "memory");
    __builtin_amdgcn_sched_barrier(0);
    __builtin_amdgcn_s_barrier();
    __builtin_amdgcn_sched_barrier(0);

    const bool pf = (t + 2 < NT);
    if (pf) {
      const int k2 = (t + 2) << 6;
      stage(Bw, bn * 256,       k2, &sB[b][0][0]);
      stage(Bw, bn * 256 + 128, k2, &sB[b][1][0]);
    }
    __builtin_amdgcn_s_setprio(1);
#pragma unroll
    for (int mt = 4; mt < 8; ++mt)
#pragma unroll
      for (int nt = 0; nt < 4; ++nt)
        acc[mt][nt] = __builtin_amdgcn_mfma_f32_16x16x32_bf16(aF[mt][0], bF[nt][0], acc[mt][nt], 0, 0, 0);
    __builtin_amdgcn_s_setprio(0);

    if (pf) {
      const int k2 = (t + 2) << 6;
      stage(A, bm * 256,       k2, &sA[b][0][0]);
      stage(A, bm * 256 + 128, k2, &sA[b][1][0]);
    }
    __builtin_amdgcn_s_setprio(1);
#pragma unroll
    for (int mt = 4; mt < 8; ++mt)
#pragma unroll
      for (int nt = 0; nt < 4; ++nt)
        acc[mt][nt] = __builtin_amdgcn_mfma_f32_16x16x32_bf16(aF[mt][1], bF[nt][1], acc[mt][nt], 0, 0, 0);
    __builtin_amdgcn_s_setprio(0);

    if (t + 1 < NT) {
      if (pf) { asm volatile("s_waitcnt vmcnt(8)" ::: "memory"); }
      else    { asm volatile("s_waitcnt vmcnt(0)" ::: "memory"); }
      __builtin_amdgcn_sched_barrier(0);
      __builtin_amdgcn_s_barrier();
      __builtin_amdgcn_sched_barrier(0);
    }
  }

#pragma unroll
  for (int mt = 0; mt < 8; ++mt) {
#pragma unroll
    for (int nt = 0; nt < 4; ++nt) {
      const int col = bn * 256 + wc * 64 + nt * 16 + l15;
#pragma unroll
      for (int i = 0; i < 4; ++i) {
        const int row = bm * 256 + wr * 128 + mt * 16 + l4 * 4 + i;
        float v = acc[mt][nt][i];
        if (BIAS) v += bias[col];
        if (GELU) {
          float x = v;
          v = 0.5f * x * (1.f + tanhf(0.7978845608028654f * (x + 0.044715f * x * x * x)));
        }
        const size_t o = (size_t)row * N + col;
        if (WF32) Cf[o] = v; else Cb[o] = f2b(v);
      }
    }
  }
}

// ---------------- GEMM 128x64 tile (2-phase dbuf), 4 waves stacked in M ----------------
template<int BIAS, int RES, int GELU, int WBF16, int ROPE>
__global__ __launch_bounds__(256) void gemm_bt64(
    const ushort_t* __restrict__ A, const ushort_t* __restrict__ Bw,
    const float* __restrict__ bias, const ushort_t* __restrict__ res,
    ushort_t* __restrict__ Cb, ushort_t* __restrict__ vtb,
    const float2* __restrict__ tab,
    int M, int N, int K)
{
  __shared__ ushort_t sA[2][128 * 32];
  __shared__ ushort_t sB[2][64 * 32];
  const int tid = threadIdx.x;
  const int lane = tid & 63, wid = tid >> 6;
  const int l15 = lane & 15, l4 = lane >> 4;

  const int gx = gridDim.x;
  const int nwg = gx * gridDim.y;
  const int orig = blockIdx.y * gx + blockIdx.x;
  const int qq = nwg >> 3, rr = nwg & 7;
  const int xcd = orig & 7, loc = orig >> 3;
  const int swz = (xcd < rr) ? (xcd * (qq + 1) + loc)
                             : (rr * (qq + 1) + (xcd - rr) * qq + loc);
  const int bm = swz % gx, bn = swz / gx;

  f32x4 acc[2][4] = {};
  const int nK = K >> 5;

#pragma unroll
  for (int j = 0; j < 2; ++j) {
    int s = wid * 128 + j * 64 + lane;
    int row = s >> 2, c8 = (s & 3) << 3;
    gload16(A + (size_t)(bm * 128 + row) * K + c8, (char*)&sA[0][0] + s * 16);
  }
  {
    int s = wid * 64 + lane;
    int row = s >> 2, c8 = (s & 3) << 3;
    gload16(Bw + (size_t)(bn * 64 + row) * K + c8, (char*)&sB[0][0] + s * 16);
  }
  __syncthreads();

  int cur = 0;
  for (int kt = 0; kt < nK; ++kt) {
    if (kt + 1 < nK) {
      const int k0 = (kt + 1) << 5;
      const int nb = cur ^ 1;
#pragma unroll
      for (int j = 0; j < 2; ++j) {
        int s = wid * 128 + j * 64 + lane;
        int row = s >> 2, c8 = (s & 3) << 3;
        gload16(A + (size_t)(bm * 128 + row) * K + k0 + c8, (char*)&sA[nb][0] + s * 16);
      }
      {
        int s = wid * 64 + lane;
        int row = s >> 2, c8 = (s & 3) << 3;
        gload16(Bw + (size_t)(bn * 64 + row) * K + k0 + c8, (char*)&sB[nb][0] + s * 16);
      }
    }
    short8 aF[2], bF[4];
#pragma unroll
    for (int mt = 0; mt < 2; ++mt)
      aF[mt] = *(const short8*)&sA[cur][(wid * 32 + mt * 16 + l15) * 32 + l4 * 8];
#pragma unroll
    for (int nt = 0; nt < 4; ++nt)
      bF[nt] = *(const short8*)&sB[cur][(nt * 16 + l15) * 32 + l4 * 8];
    __builtin_amdgcn_s_setprio(1);
#pragma unroll
    for (int mt = 0; mt < 2; ++mt)
#pragma unroll
      for (int nt = 0; nt < 4; ++nt)
        acc[mt][nt] = __builtin_amdgcn_mfma_f32_16x16x32_bf16(aF[mt], bF[nt], acc[mt][nt], 0, 0, 0);
    __builtin_amdgcn_s_setprio(0);
    __syncthreads();
    cur ^= 1;
  }

  if (ROPE) {
    const int col0 = bn * 64;
    const bool isv = (col0 >= 1280);
#pragma unroll
    for (int mt = 0; mt < 2; ++mt) {
      const int row_base = bm * 128 + wid * 32 + mt * 16 + l4 * 4;
      const int bb = row_base >> 10, t0 = row_base & (Tz - 1);
      if (isv) {
#pragma unroll
        for (int nt = 0; nt < 4; ++nt) {
          const int col = col0 + nt * 16 + l15;
          const int cm = col - 1280, hk = cm >> 6, d = cm & 63;
          ushort4 w;
          w.x = f2b(acc[mt][nt][0] + bias[col]);
          w.y = f2b(acc[mt][nt][1] + bias[col]);
          w.z = f2b(acc[mt][nt][2] + bias[col]);
          w.w = f2b(acc[mt][nt][3] + bias[col]);
          *(ushort4*)&vtb[((size_t)(bb * HKVz + hk) * 64 + d) * Tz + t0] = w;
        }
      } else {
#pragma unroll
        for (int i = 0; i < 4; ++i) {
          const int row = row_base + i;
          const int t = row & (Tz - 1);
#pragma unroll
          for (int nt = 0; nt < 2; ++nt) {
            const int col = col0 + nt * 16 + l15;
            const int jj = nt * 16 + l15;
            const float2 cs = tab[t * 32 + jj];
            const float x1 = acc[mt][nt][i] + bias[col];
            const float x2 = acc[mt][nt + 2][i] + bias[col + 32];
            Cb[(size_t)row * N + col]      = f2b(x1 * cs.x - x2 * cs.y);
            Cb[(size_t)row * N + col + 32] = f2b(x2 * cs.x + x1 * cs.y);
          }
        }
      }
    }
    return;
  }

#pragma unroll
  for (int mt = 0; mt < 2; ++mt) {
#pragma unroll
    for (int nt = 0; nt < 4; ++nt) {
      const int col = bn * 64 + nt * 16 + l15;
#pragma unroll
      for (int i = 0; i < 4; ++i) {
        const int row = bm * 128 + wid * 32 + mt * 16 + l4 * 4 + i;
        float v = acc[mt][nt][i];
        if (BIAS) v += bias[col];
        if (GELU) {
          float t = v;
          v = 0.5f * t * (1.f + tanhf(0.7978845608028654f * (t + 0.044715f * t * t * t)));
        }
        const size_t o = (size_t)row * N + col;
        if (RES) v += b2f(res[o]);
        if (WBF16) Cb[o] = f2b(v);
      }
    }
  }
}

// ---------------- flash attention (GQA, causal), swapped-operand softmax ----------------
__global__ __launch_bounds__(256, 4) void attn_k(
    const ushort_t* __restrict__ qkv, const ushort_t* __restrict__ vt,
    ushort_t* __restrict__ y)
{
  __shared__ ushort_t sK[2][64 * 64];
  __shared__ ushort_t sV[2][64 * 64];
  __shared__ unsigned sPu[4][512];
  const int bh = blockIdx.y;
  const int b = bh >> 4, h = bh & 15, hk = h >> 2;
  const int tid = threadIdx.x, lane = tid & 63, wid = tid >> 6;
  const int l15 = lane & 15, l4 = lane >> 4;
  const int xr = l15 & 7;

  for (int pass = 0; pass < 2; ++pass) {
    const int qt = pass ? (int)blockIdx.x : (Tz / 64 - 1 - (int)blockIdx.x);
    const int qrow0 = qt * 64 + wid * 16;
    const int qg = qrow0 + l15;
    const int ntile = qt + 1;

    short8 aQ[2];
#pragma unroll
    for (int ks = 0; ks < 2; ++ks)
      aQ[ks] = *(const short8*)&qkv[(size_t)(b * Tz + qrow0 + l15) * QKVz + h * 64 + ks * 32 + l4 * 8];

    float m = -1e30f, lsum = 0.f;
    f32x4 o[4] = {};

    if (pass) __syncthreads();

#pragma unroll
    for (int j = 0; j < 2; ++j) {
      int s = wid * 128 + j * 64 + lane;
      int row = s >> 3, jp = s & 7, jlog = jp ^ (row & 7);
      gload16(qkv + (size_t)(b * Tz + row) * QKVz + Ez + hk * 64 + jlog * 8, (char*)&sK[0][0] + s * 16);
      gload16(vt + (size_t)((b * HKVz + hk) * 64 + row) * Tz + jlog * 8, (char*)&sV[0][0] + s * 16);
    }

    for (int t = 0; t < ntile; ++t) {
      asm volatile("s_waitcnt vmcnt(0)" ::: "memory");
      __syncthreads();
      if (t + 1 < ntile) {
        const int nb = (t + 1) & 1;
#pragma unroll
        for (int j = 0; j < 2; ++j) {
          int s = wid * 128 + j * 64 + lane;
          int row = s >> 3, jp = s & 7, jlog = jp ^ (row & 7);
          gload16(qkv + (size_t)(b * Tz + (t + 1) * 64 + row) * QKVz + Ez + hk * 64 + jlog * 8,
                  (char*)&sK[nb][0] + s * 16);
          gload16(vt + (size_t)((b * HKVz + hk) * 64 + row) * Tz + (t + 1) * 64 + jlog * 8,
                  (char*)&sV[nb][0] + s * 16);
        }
      }
      const ushort_t* K = &sK[t & 1][0];
      const ushort_t* V = &sV[t & 1][0];

      f32x4 sacc[4] = {};
      __builtin_amdgcn_s_setprio(1);
#pragma unroll
      for (int nt = 0; nt < 4; ++nt) {
#pragma unroll
        for (int ks = 0; ks < 2; ++ks) {
          short8 aK = *(const short8*)&K[(nt * 16 + l15) * 64 + (((ks << 2) + l4) ^ xr) * 8];
          sacc[nt] = __builtin_amdgcn_mfma_f32_16x16x32_bf16(aK, aQ[ks], sacc[nt], 0, 0, 0);
        }
      }
      __builtin_amdgcn_s_setprio(0);

      float sv[4][4];
      float pmax = -1e30f;
#pragma unroll
      for (int nt = 0; nt < 4; ++nt)
#pragma unroll
        for (int i = 0; i < 4; ++i) {
          int key = t * 64 + nt * 16 + l4 * 4 + i;
          float s = sacc[nt][i] * 0.125f;
          if (key > qg) s = -1e30f;
          sv[nt][i] = s;
          pmax = fmaxf(pmax, s);
        }
      pmax = fmaxf(pmax, __shfl_xor(pmax, 16));
      pmax = fmaxf(pmax, __shfl_xor(pmax, 32));
      const float mnew = fmaxf(m, pmax);
      const float corr = __expf(m - mnew);
      float psum = 0.f;
#pragma unroll
      for (int nt = 0; nt < 4; ++nt)
#pragma unroll
        for (int i = 0; i < 4; ++i) {
          float p = __expf(sv[nt][i] - mnew);
          sv[nt][i] = p;
          psum += p;
        }
      psum += __shfl_xor(psum, 16);
      psum += __shfl_xor(psum, 32);
      lsum = lsum * corr + psum;
      m = mnew;
#pragma unroll
      for (int dt = 0; dt < 4; ++dt) o[dt] *= corr;

#pragma unroll
      for (int nt = 0; nt < 4; ++nt) {
        uint2 u;
        u.x = packbf(sv[nt][0], sv[nt][1]);
        u.y = packbf(sv[nt][2], sv[nt][3]);
        *(uint2*)&sPu[wid][l15 * 32 + (((nt * 2 + (l4 >> 1)) ^ xr) << 2) + ((l4 & 1) << 1)] = u;
      }
      short8 aP[2];
#pragma unroll
      for (int ks = 0; ks < 2; ++ks)
        aP[ks] = *(const short8*)&sPu[wid][l15 * 32 + ((((ks << 2) + l4) ^ xr) << 2)];

      __builtin_amdgcn_s_setprio(1);
#pragma unroll
      for (int dt = 0; dt < 4; ++dt) {
#pragma unroll
        for (int ks = 0; ks < 2; ++ks) {
          short8 aV = *(const short8*)&V[(dt * 16 + l15) * 64 + (((ks << 2) + l4) ^ xr) * 8];
          o[dt] = __builtin_amdgcn_mfma_f32_16x16x32_bf16(aV, aP[ks], o[dt], 0, 0, 0);
        }
      }
      __builtin_amdgcn_s_setprio(0);
    }

    const float inv = 1.f / lsum;
    const size_t yrow = (size_t)(b * Tz + qrow0 + l15) * Ez + h * 64;
#pragma unroll
    for (int dt = 0; dt < 4; ++dt) {
      ushort4 w;
      w.x = f2b(o[dt][0] * inv);
      w.y = f2b(o[dt][1] * inv);
      w.z = f2b(o[dt][2] * inv);
      w.w = f2b(o[dt][3] * inv);
      *(ushort4*)&y[yrow + dt * 16 + l4 * 4] = w;
    }
  }
}

// ---------------- LayerNorm (bf16 in -> bf16 out) ----------------
__global__ __launch_bounds__(256) void ln_bf16(
    const ushort_t* __restrict__ x, const float* __restrict__ w,
    const float* __restrict__ b, ushort_t* __restrict__ out)
{
  __shared__ float red[8];
  const int row = blockIdx.x, tid = threadIdx.x;
  ushort4 xv = *(const ushort4*)&x[(size_t)row * Ez + tid * 4];
  float v0 = b2f(xv.x), v1 = b2f(xv.y), v2 = b2f(xv.z), v3 = b2f(xv.w);
  float s = v0 + v1 + v2 + v3;
  float sq = v0 * v0 + v1 * v1 + v2 * v2 + v3 * v3;
#pragma unroll
  for (int off = 1; off < 64; off <<= 1) { s += __shfl_xor(s, off); sq += __shfl_xor(sq, off); }
  if ((tid & 63) == 0) { red[(tid >> 6) * 2] = s; red[(tid >> 6) * 2 + 1] = sq; }
  __syncthreads();
  const float ts = red[0] + red[2] + red[4] + red[6];
  const float tq = red[1] + red[3] + red[5] + red[7];
  const float mean = ts * (1.f / Ez);
  const float var = tq * (1.f / Ez) - mean * mean;
  const float rstd = rsqrtf(var + 1e-5f);
  float4 wv = *(const float4*)&w[tid * 4];
  float4 bv = *(const float4*)&b[tid * 4];
  ushort4 ov;
  ov.x = f2b((v0 - mean) * rstd * wv.x + bv.x);
  ov.y = f2b((v1 - mean) * rstd * wv.y + bv.y);
  ov.z = f2b((v2 - mean) * rstd * wv.z + bv.z);
  ov.w = f2b((v3 - mean) * rstd * wv.w + bv.w);
  *(ushort4*)&out[(size_t)row * Ez + tid * 4] = ov;
}

// ---------------- misc ----------------
__global__ __launch_bounds__(256) void embed_k(
    const int* __restrict__ idx, const float* __restrict__ wte, ushort_t* __restrict__ x)
{
  int i = blockIdx.x * 256 + threadIdx.x;
  int row = i >> 8, c = (i & 255) << 2;
  float4 v = *(const float4*)&wte[(size_t)idx[row] * Ez + c];
  ushort4 o;
  o.x = f2b(v.x); o.y = f2b(v.y); o.z = f2b(v.z); o.w = f2b(v.w);
  *(ushort4*)&x[(size_t)row * Ez + c] = o;
}

__global__ __launch_bounds__(256) void cvt_bf16(
    const float* __restrict__ in, ushort_t* __restrict__ out, int n)
{
  int i = (blockIdx.x * 256 + threadIdx.x) * 4;
  if (i >= n) return;
  float4 v = *(const float4*)&in[i];
  ushort4 o;
  o.x = f2b(v.x); o.y = f2b(v.y); o.z = f2b(v.z); o.w = f2b(v.w);
  *(ushort4*)&out[i] = o;
}

__global__ __launch_bounds__(256) void cvt_layer(
    const float* __restrict__ Wq, const float* __restrict__ Wk,
    const float* __restrict__ Wv, const float* __restrict__ Wo_,
    const float* __restrict__ Wfc_, const float* __restrict__ Wpj_,
    ushort_t* __restrict__ wqkv, ushort_t* __restrict__ wo,
    ushort_t* __restrict__ wfc, ushort_t* __restrict__ wpj)
{
  int i = (blockIdx.x * 256 + threadIdx.x) * 4;
  const float* src; ushort_t* dst; int off;
  if (i < 1048576)       { src = Wq;   dst = wqkv;           off = i; }
  else if (i < 1310720)  { src = Wk;   dst = wqkv + 1048576; off = i - 1048576; }
  else if (i < 1572864)  { src = Wv;   dst = wqkv + 1310720; off = i - 1310720; }
  else if (i < 2621440)  { src = Wo_;  dst = wo;             off = i - 1572864; }
  else if (i < 6815744)  { src = Wfc_; dst = wfc;            off = i - 2621440; }
  else                   { src = Wpj_; dst = wpj;            off = i - 6815744; }
  float4 v = *(const float4*)&src[off];
  ushort4 o;
  o.x = f2b(v.x); o.y = f2b(v.y); o.z = f2b(v.z); o.w = f2b(v.w);
  *(ushort4*)&dst[off] = o;
}

// setup: rope table (32768 items) + fused qkv bias (9216 items), one dispatch
__global__ __launch_bounds__(256) void setup_k(
    const float* __restrict__ bq, const float* __restrict__ bk,
    const float* __restrict__ bv, float2* __restrict__ tab, float* __restrict__ qbia)
{
  int i = blockIdx.x * 256 + threadIdx.x;   // Tz*32 = 32768
  int t = i >> 5, j = i & 31;
  float theta = powf(10000.0f, -(float)j / 32.0f);
  float ang = (float)(t + 1) * theta;
  tab[i] = make_float2(cosf(ang), sinf(ang));
  if (i < Lz * QKVz) {
    int l = i / QKVz, jj = i - l * QKVz;
    float v = (jj < Ez) ? bq[l * Ez + jj]
            : ((jj < Ez + EKVz) ? bk[l * EKVz + jj - Ez] : bv[l * EKVz + jj - Ez - EKVz]);
    qbia[i] = v;
  }
}

// ---------------- launchers ----------------
template<int BIAS, int RES, int GELU, int WBF16, int ROPE = 0>
static void launch_gemm64(const ushort_t* A, const ushort_t* Bw, const float* bias,
                          const ushort_t* res, ushort_t* Cb,
                          ushort_t* vtb, const float* tab,
                          int M, int N, int K, hipStream_t s)
{
  dim3 g(M / 128, N / 64);
  gemm_bt64<BIAS, RES, GELU, WBF16, ROPE><<<g, 256, 0, s>>>(
      A, Bw, bias, res, Cb, vtb, (const float2*)tab, M, N, K);
}

extern "C" void kernel_launch(void* const* d_in, const int* in_sizes, int n_in,
                              void* d_out, int out_size, void* d_ws, size_t ws_size,
                              hipStream_t stream)
{
  (void)in_sizes; (void)n_in; (void)out_size; (void)ws_size;
  const int*   idx   = (const int*)d_in[0];
  const float* wte   = (const float*)d_in[1];
  const float* Wq    = (const float*)d_in[2];
  const float* bq    = (const float*)d_in[3];
  const float* Wk    = (const float*)d_in[4];
  const float* bk    = (const float*)d_in[5];
  const float* Wv    = (const float*)d_in[6];
  const float* bv    = (const float*)d_in[7];
  const float* Wo    = (const float*)d_in[8];
  const float* bo    = (const float*)d_in[9];
  const float* ln1w  = (const float*)d_in[10];
  const float* ln1b  = (const float*)d_in[11];
  const float* ln2w  = (const float*)d_in[12];
  const float* ln2b  = (const float*)d_in[13];
  const float* Wfc   = (const float*)d_in[14];
  const float* bfc   = (const float*)d_in[15];
  const float* Wproj = (const float*)d_in[16];
  const float* bproj = (const float*)d_in[17];
  const float* lnfw  = (const float*)d_in[18];
  const float* lnfb  = (const float*)d_in[19];
  const float* lmh   = (const float*)d_in[20];
  float* out = (float*)d_out;

  char* ws = (char*)d_ws;
  size_t off = 0;
  auto alloc = [&](size_t bytes) -> void* {
    void* p = ws + off;
    off += (bytes + 255) & ~(size_t)255;
    return p;
  };
  ushort_t* wbuf  = (ushort_t*)alloc((size_t)Vz * Ez * 2);
  ushort_t* x     = (ushort_t*)alloc((size_t)Bz * Tz * Ez * 2);
  ushort_t* hb    = (ushort_t*)alloc((size_t)Bz * Tz * Ez * 2);
  ushort_t* qkvb  = (ushort_t*)alloc((size_t)Bz * Tz * QKVz * 2);
  ushort_t* vtb   = (ushort_t*)alloc((size_t)Bz * HKVz * 64 * Tz * 2);
  ushort_t* yb    = (ushort_t*)alloc((size_t)Bz * Tz * Ez * 2);
  ushort_t* ffb   = (ushort_t*)alloc((size_t)Bz * Tz * FFz * 2);
  float*    tab   = (float*)alloc((size_t)Tz * 32 * 2 * 4);
  float*    qbia  = (float*)alloc((size_t)Lz * QKVz * 4);

  ushort_t* wqkv = wbuf;
  ushort_t* wo   = wqkv + (size_t)QKVz * Ez;
  ushort_t* wfc  = wo + (size_t)Ez * Ez;
  ushort_t* wpj  = wfc + (size_t)FFz * Ez;

  const int M = Bz * Tz;

  setup_k<<<Tz * 32 / 256, 256, 0, stream>>>(bq, bk, bv, (float2*)tab, qbia);
  embed_k<<<Bz * Tz, 256, 0, stream>>>(idx, wte, x);

  for (int l = 0; l < Lz; ++l) {
    ln_bf16<<<M, 256, 0, stream>>>(x, ln1w + l * Ez, ln1b + l * Ez, hb);
    cvt_layer<<<10752, 256, 0, stream>>>(
        Wq + (size_t)l * Ez * Ez, Wk + (size_t)l * EKVz * Ez, Wv + (size_t)l * EKVz * Ez,
        Wo + (size_t)l * Ez * Ez, Wfc + (size_t)l * FFz * Ez, Wproj + (size_t)l * Ez * FFz,
        wqkv, wo, wfc, wpj);
    // QKV + fused RoPE + fused V-transpose (768 blocks = 3/CU)
    launch_gemm64<1, 0, 0, 1, 1>(hb, wqkv, qbia + l * QKVz, nullptr, qkvb, vtb, tab,
                                 M, QKVz, Ez, stream);
    attn_k<<<dim3(Tz / 128, Bz * HQz), 256, 0, stream>>>(qkvb, vtb, yb);
    // Wo + bf16 residual add -> x
    launch_gemm64<1, 1, 0, 1>(yb, wo, bo + l * Ez, x, x, nullptr, nullptr,
                              M, Ez, Ez, stream);
    ln_bf16<<<M, 256, 0, stream>>>(x, ln2w + l * Ez, ln2b + l * Ez, hb);
    // FC + GELU -> ffb (2048 blocks, high occupancy)
    launch_gemm64<1, 0, 1, 1>(hb, wfc, bfc + l * FFz, nullptr, ffb, nullptr, nullptr,
                              M, FFz, Ez, stream);
    // proj + bf16 residual add -> x
    launch_gemm64<1, 1, 0, 1>(ffb, wpj, bproj + l * Ez, x, x, nullptr, nullptr,
                              M, Ez, FFz, stream);
  }
  ln_bf16<<<M, 256, 0, stream>>>(x, lnfw, lnfb, hb);
  cvt_bf16<<<(Vz * Ez / 4 + 255) / 256, 256, 0, stream>>>(lmh, wbuf, Vz * Ez);
  {
    dim3 g(M / 256, Vz / 256);
    gemm_bt256<0, 0, 1><<<g, 512, 0, stream>>>(hb, wbuf, nullptr, out, nullptr, M, Vz, Ez);
  }
}

// Round 16
// 1693.088 us; speedup vs baseline: 1.0745x; 1.0745x over previous
//
#include <hip/hip_runtime.h>

#define Lz 6
#define Bz 4
#define Tz 1024
#define Ez 1024
#define HQz 16
#define HKVz 4
#define Dz 64
#define EKVz 256
#define Vz 32000
#define FFz 4096
#define QKVz 1536   // E + EKV + EKV

typedef __attribute__((ext_vector_type(4))) float f32x4;
typedef __attribute__((ext_vector_type(8))) short short8;
typedef unsigned short ushort_t;

__device__ inline ushort_t f2b(float f) {
  union { float f; unsigned u; } x; x.f = f;
  unsigned r = x.u + 0x7fffu + ((x.u >> 16) & 1u);
  return (ushort_t)(r >> 16);
}
__device__ inline float b2f(ushort_t u) {
  union { unsigned u; float f; } x; x.u = ((unsigned)u) << 16;
  return x.f;
}
__device__ inline unsigned packbf(float lo, float hi) {
  return (unsigned)f2b(lo) | ((unsigned)f2b(hi) << 16);
}

__device__ inline void gload16(const void* g, void* l) {
  __builtin_amdgcn_global_load_lds(
      (const __attribute__((address_space(1))) void*)g,
      (__attribute__((address_space(3))) void*)l, 16, 0, 0);
}

// ================= 256x256 4-phase GEMM (measured: lm_head ~350us, FC ~45us) =================
template<int BIAS, int GELU, int WF32>
__global__ __launch_bounds__(512, 2) void gemm_bt256(
    const ushort_t* __restrict__ A, const ushort_t* __restrict__ Bw,
    const float* __restrict__ bias,
    float* __restrict__ Cf, ushort_t* __restrict__ Cb,
    int M, int N, int K)
{
  __shared__ ushort_t sA[2][2][128 * 64];
  __shared__ ushort_t sB[2][2][128 * 64];
  const int tid = threadIdx.x;
  const int lane = tid & 63, wid = tid >> 6;
  const int wr = wid >> 2, wc = wid & 3;
  const int l15 = lane & 15, l4 = lane >> 4;

  const int gx = gridDim.x;
  const int nwg = gx * gridDim.y;
  const int orig = blockIdx.y * gx + blockIdx.x;
  const int qq = nwg >> 3, rr = nwg & 7;
  const int xcd = orig & 7, loc = orig >> 3;
  const int swz = (xcd < rr) ? (xcd * (qq + 1) + loc)
                             : (rr * (qq + 1) + (xcd - rr) * qq + loc);
  const int bm = swz % gx, bn = swz / gx;

  const int NT = K >> 6;

  auto stage = [&](const ushort_t* src, int row_base, int k0, ushort_t* dst) {
#pragma unroll
    for (int i = 0; i < 2; ++i) {
      int s = i * 512 + tid;
      int row = s >> 3, jp = s & 7;
      int jlog = jp ^ (row & 7);
      gload16(src + (size_t)(row_base + row) * K + k0 + jlog * 8, (char*)dst + s * 16);
    }
  };

  stage(A,  bm * 256,       0, &sA[0][0][0]);
  stage(A,  bm * 256 + 128, 0, &sA[0][1][0]);
  stage(Bw, bn * 256,       0, &sB[0][0][0]);
  stage(Bw, bn * 256 + 128, 0, &sB[0][1][0]);
  stage(A,  bm * 256,       64, &sA[1][0][0]);
  stage(A,  bm * 256 + 128, 64, &sA[1][1][0]);
  stage(Bw, bn * 256,       64, &sB[1][0][0]);
  stage(Bw, bn * 256 + 128, 64, &sB[1][1][0]);
  asm volatile("s_waitcnt vmcnt(8)" ::: "memory");
  __builtin_amdgcn_sched_barrier(0);
  __builtin_amdgcn_s_barrier();
  __builtin_amdgcn_sched_barrier(0);

  f32x4 acc[8][4] = {};
  const int axc = l15 & 7;

  for (int t = 0; t < NT; ++t) {
    const int b = t & 1;
    const ushort_t* pA = &sA[b][wr][0];
    const ushort_t* pB = &sB[b][wc >> 1][(wc & 1) * 64 * 64];
    short8 aF[8][2], bF[4][2];

#pragma unroll
    for (int mt = 0; mt < 4; ++mt)
#pragma unroll
      for (int ks = 0; ks < 2; ++ks)
        aF[mt][ks] = *(const short8*)&pA[(mt * 16 + l15) * 64 + (((ks << 2) + l4) ^ axc) * 8];
#pragma unroll
    for (int nt = 0; nt < 4; ++nt)
      bF[nt][0] = *(const short8*)&pB[(nt * 16 + l15) * 64 + (l4 ^ axc) * 8];
    __builtin_amdgcn_s_setprio(1);
#pragma unroll
    for (int mt = 0; mt < 4; ++mt)
#pragma unroll
      for (int nt = 0; nt < 4; ++nt)
        acc[mt][nt] = __builtin_amdgcn_mfma_f32_16x16x32_bf16(aF[mt][0], bF[nt][0], acc[mt][nt], 0, 0, 0);
    __builtin_amdgcn_s_setprio(0);

#pragma unroll
    for (int mt = 4; mt < 8; ++mt)
#pragma unroll
      for (int ks = 0; ks < 2; ++ks)
        aF[mt][ks] = *(const short8*)&pA[(mt * 16 + l15) * 64 + (((ks << 2) + l4) ^ axc) * 8];
#pragma unroll
    for (int nt = 0; nt < 4; ++nt)
      bF[nt][1] = *(const short8*)&pB[(nt * 16 + l15) * 64 + ((4 + l4) ^ axc) * 8];
    __builtin_amdgcn_s_setprio(1);
#pragma unroll
    for (int mt = 0; mt < 4; ++mt)
#pragma unroll
      for (int nt = 0; nt < 4; ++nt)
        acc[mt][nt] = __builtin_amdgcn_mfma_f32_16x16x32_bf16(aF[mt][1], bF[nt][1], acc[mt][nt], 0, 0, 0);
    __builtin_amdgcn_s_setprio(0);

    asm volatile("s_waitcnt lgkmcnt(0)" ::: "memory");
    __builtin_amdgcn_sched_barrier(0);
    __builtin_amdgcn_s_barrier();
    __builtin_amdgcn_sched_barrier(0);

    const bool pf = (t + 2 < NT);
    if (pf) {
      const int k2 = (t + 2) << 6;
      stage(Bw, bn * 256,       k2, &sB[b][0][0]);
      stage(Bw, bn * 256 + 128, k2, &sB[b][1][0]);
    }
    __builtin_amdgcn_s_setprio(1);
#pragma unroll
    for (int mt = 4; mt < 8; ++mt)
#pragma unroll
      for (int nt = 0; nt < 4; ++nt)
        acc[mt][nt] = __builtin_amdgcn_mfma_f32_16x16x32_bf16(aF[mt][0], bF[nt][0], acc[mt][nt], 0, 0, 0);
    __builtin_amdgcn_s_setprio(0);

    if (pf) {
      const int k2 = (t + 2) << 6;
      stage(A, bm * 256,       k2, &sA[b][0][0]);
      stage(A, bm * 256 + 128, k2, &sA[b][1][0]);
    }
    __builtin_amdgcn_s_setprio(1);
#pragma unroll
    for (int mt = 4; mt < 8; ++mt)
#pragma unroll
      for (int nt = 0; nt < 4; ++nt)
        acc[mt][nt] = __builtin_amdgcn_mfma_f32_16x16x32_bf16(aF[mt][1], bF[nt][1], acc[mt][nt], 0, 0, 0);
    __builtin_amdgcn_s_setprio(0);

    if (t + 1 < NT) {
      if (pf) { asm volatile("s_waitcnt vmcnt(8)" ::: "memory"); }
      else    { asm volatile("s_waitcnt vmcnt(0)" ::: "memory"); }
      __builtin_amdgcn_sched_barrier(0);
      __builtin_amdgcn_s_barrier();
      __builtin_amdgcn_sched_barrier(0);
    }
  }

#pragma unroll
  for (int mt = 0; mt < 8; ++mt) {
#pragma unroll
    for (int nt = 0; nt < 4; ++nt) {
      const int col = bn * 256 + wc * 64 + nt * 16 + l15;
#pragma unroll
      for (int i = 0; i < 4; ++i) {
        const int row = bm * 256 + wr * 128 + mt * 16 + l4 * 4 + i;
        float v = acc[mt][nt][i];
        if (BIAS) v += bias[col];
        if (GELU) {
          float x = v;
          v = 0.5f * x * (1.f + tanhf(0.7978845608028654f * (x + 0.044715f * x * x * x)));
        }
        const size_t o = (size_t)row * N + col;
        if (WF32) Cf[o] = v; else Cb[o] = f2b(v);
      }
    }
  }
}

// ---------------- GEMM 128x64 tile (2-phase dbuf), 4 waves stacked in M ----------------
// For small-N shapes only (N=1024/1536, K=1024/4096): traffic-per-output stays bounded
// while grid reaches 512-768 blocks (2-3/CU) for wave overlap.
template<int BIAS, int RES, int GELU, int WBF16, int ROPE>
__global__ __launch_bounds__(256) void gemm_bt64(
    const ushort_t* __restrict__ A, const ushort_t* __restrict__ Bw,
    const float* __restrict__ bias, const ushort_t* __restrict__ res,
    ushort_t* __restrict__ Cb, ushort_t* __restrict__ vtb,
    const float2* __restrict__ tab,
    int M, int N, int K)
{
  __shared__ ushort_t sA[2][128 * 32];
  __shared__ ushort_t sB[2][64 * 32];
  const int tid = threadIdx.x;
  const int lane = tid & 63, wid = tid >> 6;
  const int l15 = lane & 15, l4 = lane >> 4;

  const int gx = gridDim.x;
  const int nwg = gx * gridDim.y;
  const int orig = blockIdx.y * gx + blockIdx.x;
  const int qq = nwg >> 3, rr = nwg & 7;
  const int xcd = orig & 7, loc = orig >> 3;
  const int swz = (xcd < rr) ? (xcd * (qq + 1) + loc)
                             : (rr * (qq + 1) + (xcd - rr) * qq + loc);
  const int bm = swz % gx, bn = swz / gx;

  f32x4 acc[2][4] = {};
  const int nK = K >> 5;

#pragma unroll
  for (int j = 0; j < 2; ++j) {
    int s = wid * 128 + j * 64 + lane;
    int row = s >> 2, c8 = (s & 3) << 3;
    gload16(A + (size_t)(bm * 128 + row) * K + c8, (char*)&sA[0][0] + s * 16);
  }
  {
    int s = wid * 64 + lane;
    int row = s >> 2, c8 = (s & 3) << 3;
    gload16(Bw + (size_t)(bn * 64 + row) * K + c8, (char*)&sB[0][0] + s * 16);
  }
  __syncthreads();

  int cur = 0;
  for (int kt = 0; kt < nK; ++kt) {
    if (kt + 1 < nK) {
      const int k0 = (kt + 1) << 5;
      const int nb = cur ^ 1;
#pragma unroll
      for (int j = 0; j < 2; ++j) {
        int s = wid * 128 + j * 64 + lane;
        int row = s >> 2, c8 = (s & 3) << 3;
        gload16(A + (size_t)(bm * 128 + row) * K + k0 + c8, (char*)&sA[nb][0] + s * 16);
      }
      {
        int s = wid * 64 + lane;
        int row = s >> 2, c8 = (s & 3) << 3;
        gload16(Bw + (size_t)(bn * 64 + row) * K + k0 + c8, (char*)&sB[nb][0] + s * 16);
      }
    }
    short8 aF[2], bF[4];
#pragma unroll
    for (int mt = 0; mt < 2; ++mt)
      aF[mt] = *(const short8*)&sA[cur][(wid * 32 + mt * 16 + l15) * 32 + l4 * 8];
#pragma unroll
    for (int nt = 0; nt < 4; ++nt)
      bF[nt] = *(const short8*)&sB[cur][(nt * 16 + l15) * 32 + l4 * 8];
#pragma unroll
    for (int mt = 0; mt < 2; ++mt)
#pragma unroll
      for (int nt = 0; nt < 4; ++nt)
        acc[mt][nt] = __builtin_amdgcn_mfma_f32_16x16x32_bf16(aF[mt], bF[nt], acc[mt][nt], 0, 0, 0);
    __syncthreads();
    cur ^= 1;
  }

  if (ROPE) {
    const int col0 = bn * 64;
    const bool isv = (col0 >= 1280);
#pragma unroll
    for (int mt = 0; mt < 2; ++mt) {
      const int row_base = bm * 128 + wid * 32 + mt * 16 + l4 * 4;
      const int bb = row_base >> 10, t0 = row_base & (Tz - 1);
      if (isv) {
#pragma unroll
        for (int nt = 0; nt < 4; ++nt) {
          const int col = col0 + nt * 16 + l15;
          const int cm = col - 1280, hk = cm >> 6, d = cm & 63;
          ushort4 w;
          w.x = f2b(acc[mt][nt][0] + bias[col]);
          w.y = f2b(acc[mt][nt][1] + bias[col]);
          w.z = f2b(acc[mt][nt][2] + bias[col]);
          w.w = f2b(acc[mt][nt][3] + bias[col]);
          *(ushort4*)&vtb[((size_t)(bb * HKVz + hk) * 64 + d) * Tz + t0] = w;
        }
      } else {
#pragma unroll
        for (int i = 0; i < 4; ++i) {
          const int row = row_base + i;
          const int t = row & (Tz - 1);
#pragma unroll
          for (int nt = 0; nt < 2; ++nt) {
            const int col = col0 + nt * 16 + l15;
            const int jj = nt * 16 + l15;
            const float2 cs = tab[t * 32 + jj];
            const float x1 = acc[mt][nt][i] + bias[col];
            const float x2 = acc[mt][nt + 2][i] + bias[col + 32];
            Cb[(size_t)row * N + col]      = f2b(x1 * cs.x - x2 * cs.y);
            Cb[(size_t)row * N + col + 32] = f2b(x2 * cs.x + x1 * cs.y);
          }
        }
      }
    }
    return;
  }

#pragma unroll
  for (int mt = 0; mt < 2; ++mt) {
#pragma unroll
    for (int nt = 0; nt < 4; ++nt) {
      const int col = bn * 64 + nt * 16 + l15;
#pragma unroll
      for (int i = 0; i < 4; ++i) {
        const int row = bm * 128 + wid * 32 + mt * 16 + l4 * 4 + i;
        float v = acc[mt][nt][i];
        if (BIAS) v += bias[col];
        if (GELU) {
          float t = v;
          v = 0.5f * t * (1.f + tanhf(0.7978845608028654f * (t + 0.044715f * t * t * t)));
        }
        const size_t o = (size_t)row * N + col;
        if (RES) v += b2f(res[o]);
        if (WBF16) Cb[o] = f2b(v);
      }
    }
  }
}

// ---------------- flash attention (GQA, causal), swapped-operand softmax ----------------
__global__ __launch_bounds__(256, 4) void attn_k(
    const ushort_t* __restrict__ qkv, const ushort_t* __restrict__ vt,
    ushort_t* __restrict__ y)
{
  __shared__ ushort_t sK[2][64 * 64];
  __shared__ ushort_t sV[2][64 * 64];
  __shared__ unsigned sPu[4][512];
  const int bh = blockIdx.y;
  const int b = bh >> 4, h = bh & 15, hk = h >> 2;
  const int tid = threadIdx.x, lane = tid & 63, wid = tid >> 6;
  const int l15 = lane & 15, l4 = lane >> 4;
  const int xr = l15 & 7;

  for (int pass = 0; pass < 2; ++pass) {
    const int qt = pass ? (int)blockIdx.x : (Tz / 64 - 1 - (int)blockIdx.x);
    const int qrow0 = qt * 64 + wid * 16;
    const int qg = qrow0 + l15;
    const int ntile = qt + 1;

    short8 aQ[2];
#pragma unroll
    for (int ks = 0; ks < 2; ++ks)
      aQ[ks] = *(const short8*)&qkv[(size_t)(b * Tz + qrow0 + l15) * QKVz + h * 64 + ks * 32 + l4 * 8];

    float m = -1e30f, lsum = 0.f;
    f32x4 o[4] = {};

    if (pass) __syncthreads();

#pragma unroll
    for (int j = 0; j < 2; ++j) {
      int s = wid * 128 + j * 64 + lane;
      int row = s >> 3, jp = s & 7, jlog = jp ^ (row & 7);
      gload16(qkv + (size_t)(b * Tz + row) * QKVz + Ez + hk * 64 + jlog * 8, (char*)&sK[0][0] + s * 16);
      gload16(vt + (size_t)((b * HKVz + hk) * 64 + row) * Tz + jlog * 8, (char*)&sV[0][0] + s * 16);
    }

    for (int t = 0; t < ntile; ++t) {
      asm volatile("s_waitcnt vmcnt(0)" ::: "memory");
      __syncthreads();
      if (t + 1 < ntile) {
        const int nb = (t + 1) & 1;
#pragma unroll
        for (int j = 0; j < 2; ++j) {
          int s = wid * 128 + j * 64 + lane;
          int row = s >> 3, jp = s & 7, jlog = jp ^ (row & 7);
          gload16(qkv + (size_t)(b * Tz + (t + 1) * 64 + row) * QKVz + Ez + hk * 64 + jlog * 8,
                  (char*)&sK[nb][0] + s * 16);
          gload16(vt + (size_t)((b * HKVz + hk) * 64 + row) * Tz + (t + 1) * 64 + jlog * 8,
                  (char*)&sV[nb][0] + s * 16);
        }
      }
      const ushort_t* K = &sK[t & 1][0];
      const ushort_t* V = &sV[t & 1][0];

      f32x4 sacc[4] = {};
#pragma unroll
      for (int nt = 0; nt < 4; ++nt) {
#pragma unroll
        for (int ks = 0; ks < 2; ++ks) {
          short8 aK = *(const short8*)&K[(nt * 16 + l15) * 64 + (((ks << 2) + l4) ^ xr) * 8];
          sacc[nt] = __builtin_amdgcn_mfma_f32_16x16x32_bf16(aK, aQ[ks], sacc[nt], 0, 0, 0);
        }
      }

      float sv[4][4];
      float pmax = -1e30f;
#pragma unroll
      for (int nt = 0; nt < 4; ++nt)
#pragma unroll
        for (int i = 0; i < 4; ++i) {
          int key = t * 64 + nt * 16 + l4 * 4 + i;
          float s = sacc[nt][i] * 0.125f;
          if (key > qg) s = -1e30f;
          sv[nt][i] = s;
          pmax = fmaxf(pmax, s);
        }
      pmax = fmaxf(pmax, __shfl_xor(pmax, 16));
      pmax = fmaxf(pmax, __shfl_xor(pmax, 32));
      const float mnew = fmaxf(m, pmax);
      const float corr = __expf(m - mnew);
      float psum = 0.f;
#pragma unroll
      for (int nt = 0; nt < 4; ++nt)
#pragma unroll
        for (int i = 0; i < 4; ++i) {
          float p = __expf(sv[nt][i] - mnew);
          sv[nt][i] = p;
          psum += p;
        }
      psum += __shfl_xor(psum, 16);
      psum += __shfl_xor(psum, 32);
      lsum = lsum * corr + psum;
      m = mnew;
#pragma unroll
      for (int dt = 0; dt < 4; ++dt) o[dt] *= corr;

#pragma unroll
      for (int nt = 0; nt < 4; ++nt) {
        uint2 u;
        u.x = packbf(sv[nt][0], sv[nt][1]);
        u.y = packbf(sv[nt][2], sv[nt][3]);
        *(uint2*)&sPu[wid][l15 * 32 + (((nt * 2 + (l4 >> 1)) ^ xr) << 2) + ((l4 & 1) << 1)] = u;
      }
      short8 aP[2];
#pragma unroll
      for (int ks = 0; ks < 2; ++ks)
        aP[ks] = *(const short8*)&sPu[wid][l15 * 32 + ((((ks << 2) + l4) ^ xr) << 2)];

#pragma unroll
      for (int dt = 0; dt < 4; ++dt) {
#pragma unroll
        for (int ks = 0; ks < 2; ++ks) {
          short8 aV = *(const short8*)&V[(dt * 16 + l15) * 64 + (((ks << 2) + l4) ^ xr) * 8];
          o[dt] = __builtin_amdgcn_mfma_f32_16x16x32_bf16(aV, aP[ks], o[dt], 0, 0, 0);
        }
      }
    }

    const float inv = 1.f / lsum;
    const size_t yrow = (size_t)(b * Tz + qrow0 + l15) * Ez + h * 64;
#pragma unroll
    for (int dt = 0; dt < 4; ++dt) {
      ushort4 w;
      w.x = f2b(o[dt][0] * inv);
      w.y = f2b(o[dt][1] * inv);
      w.z = f2b(o[dt][2] * inv);
      w.w = f2b(o[dt][3] * inv);
      *(ushort4*)&y[yrow + dt * 16 + l4 * 4] = w;
    }
  }
}

// ---------------- LayerNorm (bf16 in -> bf16 out) ----------------
__global__ __launch_bounds__(256) void ln_bf16(
    const ushort_t* __restrict__ x, const float* __restrict__ w,
    const float* __restrict__ b, ushort_t* __restrict__ out)
{
  __shared__ float red[8];
  const int row = blockIdx.x, tid = threadIdx.x;
  ushort4 xv = *(const ushort4*)&x[(size_t)row * Ez + tid * 4];
  float v0 = b2f(xv.x), v1 = b2f(xv.y), v2 = b2f(xv.z), v3 = b2f(xv.w);
  float s = v0 + v1 + v2 + v3;
  float sq = v0 * v0 + v1 * v1 + v2 * v2 + v3 * v3;
#pragma unroll
  for (int off = 1; off < 64; off <<= 1) { s += __shfl_xor(s, off); sq += __shfl_xor(sq, off); }
  if ((tid & 63) == 0) { red[(tid >> 6) * 2] = s; red[(tid >> 6) * 2 + 1] = sq; }
  __syncthreads();
  const float ts = red[0] + red[2] + red[4] + red[6];
  const float tq = red[1] + red[3] + red[5] + red[7];
  const float mean = ts * (1.f / Ez);
  const float var = tq * (1.f / Ez) - mean * mean;
  const float rstd = rsqrtf(var + 1e-5f);
  float4 wv = *(const float4*)&w[tid * 4];
  float4 bv = *(const float4*)&b[tid * 4];
  ushort4 ov;
  ov.x = f2b((v0 - mean) * rstd * wv.x + bv.x);
  ov.y = f2b((v1 - mean) * rstd * wv.y + bv.y);
  ov.z = f2b((v2 - mean) * rstd * wv.z + bv.z);
  ov.w = f2b((v3 - mean) * rstd * wv.w + bv.w);
  *(ushort4*)&out[(size_t)row * Ez + tid * 4] = ov;
}

// ---------------- misc ----------------
__global__ __launch_bounds__(256) void embed_k(
    const int* __restrict__ idx, const float* __restrict__ wte, ushort_t* __restrict__ x)
{
  int i = blockIdx.x * 256 + threadIdx.x;
  int row = i >> 8, c = (i & 255) << 2;
  float4 v = *(const float4*)&wte[(size_t)idx[row] * Ez + c];
  ushort4 o;
  o.x = f2b(v.x); o.y = f2b(v.y); o.z = f2b(v.z); o.w = f2b(v.w);
  *(ushort4*)&x[(size_t)row * Ez + c] = o;
}

__global__ __launch_bounds__(256) void cvt_bf16(
    const float* __restrict__ in, ushort_t* __restrict__ out, int n)
{
  int i = (blockIdx.x * 256 + threadIdx.x) * 4;
  if (i >= n) return;
  float4 v = *(const float4*)&in[i];
  ushort4 o;
  o.x = f2b(v.x); o.y = f2b(v.y); o.z = f2b(v.z); o.w = f2b(v.w);
  *(ushort4*)&out[i] = o;
}

__global__ __launch_bounds__(256) void cvt_layer(
    const float* __restrict__ Wq, const float* __restrict__ Wk,
    const float* __restrict__ Wv, const float* __restrict__ Wo_,
    const float* __restrict__ Wfc_, const float* __restrict__ Wpj_,
    ushort_t* __restrict__ wqkv, ushort_t* __restrict__ wo,
    ushort_t* __restrict__ wfc, ushort_t* __restrict__ wpj)
{
  int i = (blockIdx.x * 256 + threadIdx.x) * 4;
  const float* src; ushort_t* dst; int off;
  if (i < 1048576)       { src = Wq;   dst = wqkv;           off = i; }
  else if (i < 1310720)  { src = Wk;   dst = wqkv + 1048576; off = i - 1048576; }
  else if (i < 1572864)  { src = Wv;   dst = wqkv + 1310720; off = i - 1310720; }
  else if (i < 2621440)  { src = Wo_;  dst = wo;             off = i - 1572864; }
  else if (i < 6815744)  { src = Wfc_; dst = wfc;            off = i - 2621440; }
  else                   { src = Wpj_; dst = wpj;            off = i - 6815744; }
  float4 v = *(const float4*)&src[off];
  ushort4 o;
  o.x = f2b(v.x); o.y = f2b(v.y); o.z = f2b(v.z); o.w = f2b(v.w);
  *(ushort4*)&dst[off] = o;
}

// setup: rope table (32768 items) + fused qkv bias (9216 items), one dispatch
__global__ __launch_bounds__(256) void setup_k(
    const float* __restrict__ bq, const float* __restrict__ bk,
    const float* __restrict__ bv, float2* __restrict__ tab, float* __restrict__ qbia)
{
  int i = blockIdx.x * 256 + threadIdx.x;   // Tz*32 = 32768
  int t = i >> 5, j = i & 31;
  float theta = powf(10000.0f, -(float)j / 32.0f);
  float ang = (float)(t + 1) * theta;
  tab[i] = make_float2(cosf(ang), sinf(ang));
  if (i < Lz * QKVz) {
    int l = i / QKVz, jj = i - l * QKVz;
    float v = (jj < Ez) ? bq[l * Ez + jj]
            : ((jj < Ez + EKVz) ? bk[l * EKVz + jj - Ez] : bv[l * EKVz + jj - Ez - EKVz]);
    qbia[i] = v;
  }
}

// ---------------- launchers ----------------
template<int BIAS, int RES, int GELU, int WBF16, int ROPE = 0>
static void launch_gemm64(const ushort_t* A, const ushort_t* Bw, const float* bias,
                          const ushort_t* res, ushort_t* Cb,
                          ushort_t* vtb, const float* tab,
                          int M, int N, int K, hipStream_t s)
{
  dim3 g(M / 128, N / 64);
  gemm_bt64<BIAS, RES, GELU, WBF16, ROPE><<<g, 256, 0, s>>>(
      A, Bw, bias, res, Cb, vtb, (const float2*)tab, M, N, K);
}

extern "C" void kernel_launch(void* const* d_in, const int* in_sizes, int n_in,
                              void* d_out, int out_size, void* d_ws, size_t ws_size,
                              hipStream_t stream)
{
  (void)in_sizes; (void)n_in; (void)out_size; (void)ws_size;
  const int*   idx   = (const int*)d_in[0];
  const float* wte   = (const float*)d_in[1];
  const float* Wq    = (const float*)d_in[2];
  const float* bq    = (const float*)d_in[3];
  const float* Wk    = (const float*)d_in[4];
  const float* bk    = (const float*)d_in[5];
  const float* Wv    = (const float*)d_in[6];
  const float* bv    = (const float*)d_in[7];
  const float* Wo    = (const float*)d_in[8];
  const float* bo    = (const float*)d_in[9];
  const float* ln1w  = (const float*)d_in[10];
  const float* ln1b  = (const float*)d_in[11];
  const float* ln2w  = (const float*)d_in[12];
  const float* ln2b  = (const float*)d_in[13];
  const float* Wfc   = (const float*)d_in[14];
  const float* bfc   = (const float*)d_in[15];
  const float* Wproj = (const float*)d_in[16];
  const float* bproj = (const float*)d_in[17];
  const float* lnfw  = (const float*)d_in[18];
  const float* lnfb  = (const float*)d_in[19];
  const float* lmh   = (const float*)d_in[20];
  float* out = (float*)d_out;

  char* ws = (char*)d_ws;
  size_t off = 0;
  auto alloc = [&](size_t bytes) -> void* {
    void* p = ws + off;
    off += (bytes + 255) & ~(size_t)255;
    return p;
  };
  ushort_t* wbuf  = (ushort_t*)alloc((size_t)Vz * Ez * 2);
  ushort_t* x     = (ushort_t*)alloc((size_t)Bz * Tz * Ez * 2);
  ushort_t* hb    = (ushort_t*)alloc((size_t)Bz * Tz * Ez * 2);
  ushort_t* qkvb  = (ushort_t*)alloc((size_t)Bz * Tz * QKVz * 2);
  ushort_t* vtb   = (ushort_t*)alloc((size_t)Bz * HKVz * 64 * Tz * 2);
  ushort_t* yb    = (ushort_t*)alloc((size_t)Bz * Tz * Ez * 2);
  ushort_t* ffb   = (ushort_t*)alloc((size_t)Bz * Tz * FFz * 2);
  float*    tab   = (float*)alloc((size_t)Tz * 32 * 2 * 4);
  float*    qbia  = (float*)alloc((size_t)Lz * QKVz * 4);

  ushort_t* wqkv = wbuf;
  ushort_t* wo   = wqkv + (size_t)QKVz * Ez;
  ushort_t* wfc  = wo + (size_t)Ez * Ez;
  ushort_t* wpj  = wfc + (size_t)FFz * Ez;

  const int M = Bz * Tz;

  setup_k<<<Tz * 32 / 256, 256, 0, stream>>>(bq, bk, bv, (float2*)tab, qbia);
  embed_k<<<Bz * Tz, 256, 0, stream>>>(idx, wte, x);

  for (int l = 0; l < Lz; ++l) {
    ln_bf16<<<M, 256, 0, stream>>>(x, ln1w + l * Ez, ln1b + l * Ez, hb);
    cvt_layer<<<10752, 256, 0, stream>>>(
        Wq + (size_t)l * Ez * Ez, Wk + (size_t)l * EKVz * Ez, Wv + (size_t)l * EKVz * Ez,
        Wo + (size_t)l * Ez * Ez, Wfc + (size_t)l * FFz * Ez, Wproj + (size_t)l * Ez * FFz,
        wqkv, wo, wfc, wpj);
    // QKV + fused RoPE + fused V-transpose (768 blocks = 3/CU)
    launch_gemm64<1, 0, 0, 1, 1>(hb, wqkv, qbia + l * QKVz, nullptr, qkvb, vtb, tab,
                                 M, QKVz, Ez, stream);
    attn_k<<<dim3(Tz / 128, Bz * HQz), 256, 0, stream>>>(qkvb, vtb, yb);
    // Wo + bf16 residual add -> x
    launch_gemm64<1, 1, 0, 1>(yb, wo, bo + l * Ez, x, x, nullptr, nullptr,
                              M, Ez, Ez, stream);
    ln_bf16<<<M, 256, 0, stream>>>(x, ln2w + l * Ez, ln2b + l * Ez, hb);
    // FC + GELU on bt256 (traffic-optimal for N=4096)
    {
      dim3 g(M / 256, FFz / 256);
      gemm_bt256<1, 1, 0><<<g, 512, 0, stream>>>(hb, wfc, bfc + l * FFz, nullptr, ffb, M, FFz, Ez);
    }
    // proj + bf16 residual add -> x
    launch_gemm64<1, 1, 0, 1>(ffb, wpj, bproj + l * Ez, x, x, nullptr, nullptr,
                              M, Ez, FFz, stream);
  }
  ln_bf16<<<M, 256, 0, stream>>>(x, lnfw, lnfb, hb);
  cvt_bf16<<<(Vz * Ez / 4 + 255) / 256, 256, 0, stream>>>(lmh, wbuf, Vz * Ez);
  {
    dim3 g(M / 256, Vz / 256);
    gemm_bt256<0, 0, 1><<<g, 512, 0, stream>>>(hb, wbuf, nullptr, out, nullptr, M, Vz, Ez);
  }
}

// Round 17
// 1587.452 us; speedup vs baseline: 1.1460x; 1.0665x over previous
//
#include <hip/hip_runtime.h>

#define Lz 6
#define Bz 4
#define Tz 1024
#define Ez 1024
#define HQz 16
#define HKVz 4
#define Dz 64
#define EKVz 256
#define Vz 32000
#define FFz 4096
#define QKVz 1536   // E + EKV + EKV

typedef __attribute__((ext_vector_type(4))) float f32x4;
typedef __attribute__((ext_vector_type(8))) short short8;
typedef unsigned short ushort_t;

__device__ inline ushort_t f2b(float f) {
  union { float f; unsigned u; } x; x.f = f;
  unsigned r = x.u + 0x7fffu + ((x.u >> 16) & 1u);
  return (ushort_t)(r >> 16);
}
__device__ inline float b2f(ushort_t u) {
  union { unsigned u; float f; } x; x.u = ((unsigned)u) << 16;
  return x.f;
}
__device__ inline unsigned packbf(float lo, float hi) {
  return (unsigned)f2b(lo) | ((unsigned)f2b(hi) << 16);
}

__device__ inline void gload16(const void* g, void* l) {
  __builtin_amdgcn_global_load_lds(
      (const __attribute__((address_space(1))) void*)g,
      (__attribute__((address_space(3))) void*)l, 16, 0, 0);
}

// ================= 256x256 4-phase GEMM (measured: lm_head ~350us, FC ~45us) =================
template<int BIAS, int GELU, int WF32>
__global__ __launch_bounds__(512, 2) void gemm_bt256(
    const ushort_t* __restrict__ A, const ushort_t* __restrict__ Bw,
    const float* __restrict__ bias,
    float* __restrict__ Cf, ushort_t* __restrict__ Cb,
    int M, int N, int K)
{
  __shared__ ushort_t sA[2][2][128 * 64];
  __shared__ ushort_t sB[2][2][128 * 64];
  const int tid = threadIdx.x;
  const int lane = tid & 63, wid = tid >> 6;
  const int wr = wid >> 2, wc = wid & 3;
  const int l15 = lane & 15, l4 = lane >> 4;

  const int gx = gridDim.x;
  const int nwg = gx * gridDim.y;
  const int orig = blockIdx.y * gx + blockIdx.x;
  const int qq = nwg >> 3, rr = nwg & 7;
  const int xcd = orig & 7, loc = orig >> 3;
  const int swz = (xcd < rr) ? (xcd * (qq + 1) + loc)
                             : (rr * (qq + 1) + (xcd - rr) * qq + loc);
  const int bm = swz % gx, bn = swz / gx;

  const int NT = K >> 6;

  auto stage = [&](const ushort_t* src, int row_base, int k0, ushort_t* dst) {
#pragma unroll
    for (int i = 0; i < 2; ++i) {
      int s = i * 512 + tid;
      int row = s >> 3, jp = s & 7;
      int jlog = jp ^ (row & 7);
      gload16(src + (size_t)(row_base + row) * K + k0 + jlog * 8, (char*)dst + s * 16);
    }
  };

  stage(A,  bm * 256,       0, &sA[0][0][0]);
  stage(A,  bm * 256 + 128, 0, &sA[0][1][0]);
  stage(Bw, bn * 256,       0, &sB[0][0][0]);
  stage(Bw, bn * 256 + 128, 0, &sB[0][1][0]);
  stage(A,  bm * 256,       64, &sA[1][0][0]);
  stage(A,  bm * 256 + 128, 64, &sA[1][1][0]);
  stage(Bw, bn * 256,       64, &sB[1][0][0]);
  stage(Bw, bn * 256 + 128, 64, &sB[1][1][0]);
  asm volatile("s_waitcnt vmcnt(8)" ::: "memory");
  __builtin_amdgcn_sched_barrier(0);
  __builtin_amdgcn_s_barrier();
  __builtin_amdgcn_sched_barrier(0);

  f32x4 acc[8][4] = {};
  const int axc = l15 & 7;

  for (int t = 0; t < NT; ++t) {
    const int b = t & 1;
    const ushort_t* pA = &sA[b][wr][0];
    const ushort_t* pB = &sB[b][wc >> 1][(wc & 1) * 64 * 64];
    short8 aF[8][2], bF[4][2];

#pragma unroll
    for (int mt = 0; mt < 4; ++mt)
#pragma unroll
      for (int ks = 0; ks < 2; ++ks)
        aF[mt][ks] = *(const short8*)&pA[(mt * 16 + l15) * 64 + (((ks << 2) + l4) ^ axc) * 8];
#pragma unroll
    for (int nt = 0; nt < 4; ++nt)
      bF[nt][0] = *(const short8*)&pB[(nt * 16 + l15) * 64 + (l4 ^ axc) * 8];
    __builtin_amdgcn_s_setprio(1);
#pragma unroll
    for (int mt = 0; mt < 4; ++mt)
#pragma unroll
      for (int nt = 0; nt < 4; ++nt)
        acc[mt][nt] = __builtin_amdgcn_mfma_f32_16x16x32_bf16(aF[mt][0], bF[nt][0], acc[mt][nt], 0, 0, 0);
    __builtin_amdgcn_s_setprio(0);

#pragma unroll
    for (int mt = 4; mt < 8; ++mt)
#pragma unroll
      for (int ks = 0; ks < 2; ++ks)
        aF[mt][ks] = *(const short8*)&pA[(mt * 16 + l15) * 64 + (((ks << 2) + l4) ^ axc) * 8];
#pragma unroll
    for (int nt = 0; nt < 4; ++nt)
      bF[nt][1] = *(const short8*)&pB[(nt * 16 + l15) * 64 + ((4 + l4) ^ axc) * 8];
    __builtin_amdgcn_s_setprio(1);
#pragma unroll
    for (int mt = 0; mt < 4; ++mt)
#pragma unroll
      for (int nt = 0; nt < 4; ++nt)
        acc[mt][nt] = __builtin_amdgcn_mfma_f32_16x16x32_bf16(aF[mt][1], bF[nt][1], acc[mt][nt], 0, 0, 0);
    __builtin_amdgcn_s_setprio(0);

    asm volatile("s_waitcnt lgkmcnt(0)" ::: "memory");
    __builtin_amdgcn_sched_barrier(0);
    __builtin_amdgcn_s_barrier();
    __builtin_amdgcn_sched_barrier(0);

    const bool pf = (t + 2 < NT);
    if (pf) {
      const int k2 = (t + 2) << 6;
      stage(Bw, bn * 256,       k2, &sB[b][0][0]);
      stage(Bw, bn * 256 + 128, k2, &sB[b][1][0]);
    }
    __builtin_amdgcn_s_setprio(1);
#pragma unroll
    for (int mt = 4; mt < 8; ++mt)
#pragma unroll
      for (int nt = 0; nt < 4; ++nt)
        acc[mt][nt] = __builtin_amdgcn_mfma_f32_16x16x32_bf16(aF[mt][0], bF[nt][0], acc[mt][nt], 0, 0, 0);
    __builtin_amdgcn_s_setprio(0);

    if (pf) {
      const int k2 = (t + 2) << 6;
      stage(A, bm * 256,       k2, &sA[b][0][0]);
      stage(A, bm * 256 + 128, k2, &sA[b][1][0]);
    }
    __builtin_amdgcn_s_setprio(1);
#pragma unroll
    for (int mt = 4; mt < 8; ++mt)
#pragma unroll
      for (int nt = 0; nt < 4; ++nt)
        acc[mt][nt] = __builtin_amdgcn_mfma_f32_16x16x32_bf16(aF[mt][1], bF[nt][1], acc[mt][nt], 0, 0, 0);
    __builtin_amdgcn_s_setprio(0);

    if (t + 1 < NT) {
      if (pf) { asm volatile("s_waitcnt vmcnt(8)" ::: "memory"); }
      else    { asm volatile("s_waitcnt vmcnt(0)" ::: "memory"); }
      __builtin_amdgcn_sched_barrier(0);
      __builtin_amdgcn_s_barrier();
      __builtin_amdgcn_sched_barrier(0);
    }
  }

#pragma unroll
  for (int mt = 0; mt < 8; ++mt) {
#pragma unroll
    for (int nt = 0; nt < 4; ++nt) {
      const int col = bn * 256 + wc * 64 + nt * 16 + l15;
#pragma unroll
      for (int i = 0; i < 4; ++i) {
        const int row = bm * 256 + wr * 128 + mt * 16 + l4 * 4 + i;
        float v = acc[mt][nt][i];
        if (BIAS) v += bias[col];
        if (GELU) {
          float x = v;
          v = 0.5f * x * (1.f + tanhf(0.7978845608028654f * (x + 0.044715f * x * x * x)));
        }
        const size_t o = (size_t)row * N + col;
        if (WF32) Cf[o] = v; else Cb[o] = f2b(v);
      }
    }
  }
}

// ---------------- GEMM 128x64 tile, BK=64, conflict-free 3-bit XOR swizzle ----------------
// 4 waves stacked in M (32 rows x 64 cols each). Rows are 64 elems = 8 chunks; read chunk
// (ks*4+l4) ^ (l15&7) with pre-swizzled gload source (rule #21) -> 0 bank conflicts
// (bt256's measured pattern). 16 MFMA/wave per barrier pair. LDS 48KB -> 3 blocks/CU.
template<int BIAS, int RES, int GELU, int WBF16, int ROPE>
__global__ __launch_bounds__(256) void gemm_bt64(
    const ushort_t* __restrict__ A, const ushort_t* __restrict__ Bw,
    const float* __restrict__ bias, const ushort_t* __restrict__ res,
    ushort_t* __restrict__ Cb, ushort_t* __restrict__ vtb,
    const float2* __restrict__ tab,
    int M, int N, int K)
{
  __shared__ ushort_t sA[2][128 * 64];
  __shared__ ushort_t sB[2][64 * 64];
  const int tid = threadIdx.x;
  const int lane = tid & 63, wid = tid >> 6;
  const int l15 = lane & 15, l4 = lane >> 4;
  const int xr = l15 & 7;

  const int gx = gridDim.x;
  const int nwg = gx * gridDim.y;
  const int orig = blockIdx.y * gx + blockIdx.x;
  const int qq = nwg >> 3, rr = nwg & 7;
  const int xcd = orig & 7, loc = orig >> 3;
  const int swz = (xcd < rr) ? (xcd * (qq + 1) + loc)
                             : (rr * (qq + 1) + (xcd - rr) * qq + loc);
  const int bm = swz % gx, bn = swz / gx;

  f32x4 acc[2][4] = {};
  const int nK = K >> 6;

  auto stageA = [&](int k0, ushort_t* dst) {
#pragma unroll
    for (int i = 0; i < 4; ++i) {
      int s = i * 256 + tid;                 // 1024 slots: row = s>>3, chunk = s&7
      int row = s >> 3, jp = s & 7;
      int jlog = jp ^ (row & 7);
      gload16(A + (size_t)(bm * 128 + row) * K + k0 + jlog * 8, (char*)dst + s * 16);
    }
  };
  auto stageB = [&](int k0, ushort_t* dst) {
#pragma unroll
    for (int i = 0; i < 2; ++i) {
      int s = i * 256 + tid;                 // 512 slots
      int row = s >> 3, jp = s & 7;
      int jlog = jp ^ (row & 7);
      gload16(Bw + (size_t)(bn * 64 + row) * K + k0 + jlog * 8, (char*)dst + s * 16);
    }
  };

  stageA(0, &sA[0][0]);
  stageB(0, &sB[0][0]);
  __syncthreads();

  int cur = 0;
  for (int kt = 0; kt < nK; ++kt) {
    if (kt + 1 < nK) {
      const int k0 = (kt + 1) << 6;
      stageA(k0, &sA[cur ^ 1][0]);
      stageB(k0, &sB[cur ^ 1][0]);
    }
    short8 aF[2][2], bF[4][2];
#pragma unroll
    for (int mt = 0; mt < 2; ++mt)
#pragma unroll
      for (int ks = 0; ks < 2; ++ks)
        aF[mt][ks] = *(const short8*)&sA[cur][(wid * 32 + mt * 16 + l15) * 64 + (((ks << 2) + l4) ^ xr) * 8];
#pragma unroll
    for (int nt = 0; nt < 4; ++nt)
#pragma unroll
      for (int ks = 0; ks < 2; ++ks)
        bF[nt][ks] = *(const short8*)&sB[cur][(nt * 16 + l15) * 64 + (((ks << 2) + l4) ^ xr) * 8];
#pragma unroll
    for (int mt = 0; mt < 2; ++mt)
#pragma unroll
      for (int nt = 0; nt < 4; ++nt)
#pragma unroll
        for (int ks = 0; ks < 2; ++ks)
          acc[mt][nt] = __builtin_amdgcn_mfma_f32_16x16x32_bf16(aF[mt][ks], bF[nt][ks], acc[mt][nt], 0, 0, 0);
    __syncthreads();
    cur ^= 1;
  }

  if (ROPE) {
    const int col0 = bn * 64;
    const bool isv = (col0 >= 1280);
#pragma unroll
    for (int mt = 0; mt < 2; ++mt) {
      const int row_base = bm * 128 + wid * 32 + mt * 16 + l4 * 4;
      const int bb = row_base >> 10, t0 = row_base & (Tz - 1);
      if (isv) {
#pragma unroll
        for (int nt = 0; nt < 4; ++nt) {
          const int col = col0 + nt * 16 + l15;
          const int cm = col - 1280, hk = cm >> 6, d = cm & 63;
          ushort4 w;
          w.x = f2b(acc[mt][nt][0] + bias[col]);
          w.y = f2b(acc[mt][nt][1] + bias[col]);
          w.z = f2b(acc[mt][nt][2] + bias[col]);
          w.w = f2b(acc[mt][nt][3] + bias[col]);
          *(ushort4*)&vtb[((size_t)(bb * HKVz + hk) * 64 + d) * Tz + t0] = w;
        }
      } else {
#pragma unroll
        for (int i = 0; i < 4; ++i) {
          const int row = row_base + i;
          const int t = row & (Tz - 1);
#pragma unroll
          for (int nt = 0; nt < 2; ++nt) {
            const int col = col0 + nt * 16 + l15;
            const int jj = nt * 16 + l15;
            const float2 cs = tab[t * 32 + jj];
            const float x1 = acc[mt][nt][i] + bias[col];
            const float x2 = acc[mt][nt + 2][i] + bias[col + 32];
            Cb[(size_t)row * N + col]      = f2b(x1 * cs.x - x2 * cs.y);
            Cb[(size_t)row * N + col + 32] = f2b(x2 * cs.x + x1 * cs.y);
          }
        }
      }
    }
    return;
  }

#pragma unroll
  for (int mt = 0; mt < 2; ++mt) {
#pragma unroll
    for (int nt = 0; nt < 4; ++nt) {
      const int col = bn * 64 + nt * 16 + l15;
#pragma unroll
      for (int i = 0; i < 4; ++i) {
        const int row = bm * 128 + wid * 32 + mt * 16 + l4 * 4 + i;
        float v = acc[mt][nt][i];
        if (BIAS) v += bias[col];
        if (GELU) {
          float t = v;
          v = 0.5f * t * (1.f + tanhf(0.7978845608028654f * (t + 0.044715f * t * t * t)));
        }
        const size_t o = (size_t)row * N + col;
        if (RES) v += b2f(res[o]);
        if (WBF16) Cb[o] = f2b(v);
      }
    }
  }
}

// ---------------- flash attention (GQA, causal), swapped-operand softmax ----------------
__global__ __launch_bounds__(256, 4) void attn_k(
    const ushort_t* __restrict__ qkv, const ushort_t* __restrict__ vt,
    ushort_t* __restrict__ y)
{
  __shared__ ushort_t sK[2][64 * 64];
  __shared__ ushort_t sV[2][64 * 64];
  __shared__ unsigned sPu[4][512];
  const int bh = blockIdx.y;
  const int b = bh >> 4, h = bh & 15, hk = h >> 2;
  const int tid = threadIdx.x, lane = tid & 63, wid = tid >> 6;
  const int l15 = lane & 15, l4 = lane >> 4;
  const int xr = l15 & 7;

  for (int pass = 0; pass < 2; ++pass) {
    const int qt = pass ? (int)blockIdx.x : (Tz / 64 - 1 - (int)blockIdx.x);
    const int qrow0 = qt * 64 + wid * 16;
    const int qg = qrow0 + l15;
    const int ntile = qt + 1;

    short8 aQ[2];
#pragma unroll
    for (int ks = 0; ks < 2; ++ks)
      aQ[ks] = *(const short8*)&qkv[(size_t)(b * Tz + qrow0 + l15) * QKVz + h * 64 + ks * 32 + l4 * 8];

    float m = -1e30f, lsum = 0.f;
    f32x4 o[4] = {};

    if (pass) __syncthreads();

#pragma unroll
    for (int j = 0; j < 2; ++j) {
      int s = wid * 128 + j * 64 + lane;
      int row = s >> 3, jp = s & 7, jlog = jp ^ (row & 7);
      gload16(qkv + (size_t)(b * Tz + row) * QKVz + Ez + hk * 64 + jlog * 8, (char*)&sK[0][0] + s * 16);
      gload16(vt + (size_t)((b * HKVz + hk) * 64 + row) * Tz + jlog * 8, (char*)&sV[0][0] + s * 16);
    }

    for (int t = 0; t < ntile; ++t) {
      asm volatile("s_waitcnt vmcnt(0)" ::: "memory");
      __syncthreads();
      if (t + 1 < ntile) {
        const int nb = (t + 1) & 1;
#pragma unroll
        for (int j = 0; j < 2; ++j) {
          int s = wid * 128 + j * 64 + lane;
          int row = s >> 3, jp = s & 7, jlog = jp ^ (row & 7);
          gload16(qkv + (size_t)(b * Tz + (t + 1) * 64 + row) * QKVz + Ez + hk * 64 + jlog * 8,
                  (char*)&sK[nb][0] + s * 16);
          gload16(vt + (size_t)((b * HKVz + hk) * 64 + row) * Tz + (t + 1) * 64 + jlog * 8,
                  (char*)&sV[nb][0] + s * 16);
        }
      }
      const ushort_t* K = &sK[t & 1][0];
      const ushort_t* V = &sV[t & 1][0];

      f32x4 sacc[4] = {};
#pragma unroll
      for (int nt = 0; nt < 4; ++nt) {
#pragma unroll
        for (int ks = 0; ks < 2; ++ks) {
          short8 aK = *(const short8*)&K[(nt * 16 + l15) * 64 + (((ks << 2) + l4) ^ xr) * 8];
          sacc[nt] = __builtin_amdgcn_mfma_f32_16x16x32_bf16(aK, aQ[ks], sacc[nt], 0, 0, 0);
        }
      }

      float sv[4][4];
      float pmax = -1e30f;
#pragma unroll
      for (int nt = 0; nt < 4; ++nt)
#pragma unroll
        for (int i = 0; i < 4; ++i) {
          int key = t * 64 + nt * 16 + l4 * 4 + i;
          float s = sacc[nt][i] * 0.125f;
          if (key > qg) s = -1e30f;
          sv[nt][i] = s;
          pmax = fmaxf(pmax, s);
        }
      pmax = fmaxf(pmax, __shfl_xor(pmax, 16));
      pmax = fmaxf(pmax, __shfl_xor(pmax, 32));
      const float mnew = fmaxf(m, pmax);
      const float corr = __expf(m - mnew);
      float psum = 0.f;
#pragma unroll
      for (int nt = 0; nt < 4; ++nt)
#pragma unroll
        for (int i = 0; i < 4; ++i) {
          float p = __expf(sv[nt][i] - mnew);
          sv[nt][i] = p;
          psum += p;
        }
      psum += __shfl_xor(psum, 16);
      psum += __shfl_xor(psum, 32);
      lsum = lsum * corr + psum;
      m = mnew;
#pragma unroll
      for (int dt = 0; dt < 4; ++dt) o[dt] *= corr;

#pragma unroll
      for (int nt = 0; nt < 4; ++nt) {
        uint2 u;
        u.x = packbf(sv[nt][0], sv[nt][1]);
        u.y = packbf(sv[nt][2], sv[nt][3]);
        *(uint2*)&sPu[wid][l15 * 32 + (((nt * 2 + (l4 >> 1)) ^ xr) << 2) + ((l4 & 1) << 1)] = u;
      }
      short8 aP[2];
#pragma unroll
      for (int ks = 0; ks < 2; ++ks)
        aP[ks] = *(const short8*)&sPu[wid][l15 * 32 + ((((ks << 2) + l4) ^ xr) << 2)];

#pragma unroll
      for (int dt = 0; dt < 4; ++dt) {
#pragma unroll
        for (int ks = 0; ks < 2; ++ks) {
          short8 aV = *(const short8*)&V[(dt * 16 + l15) * 64 + (((ks << 2) + l4) ^ xr) * 8];
          o[dt] = __builtin_amdgcn_mfma_f32_16x16x32_bf16(aV, aP[ks], o[dt], 0, 0, 0);
        }
      }
    }

    const float inv = 1.f / lsum;
    const size_t yrow = (size_t)(b * Tz + qrow0 + l15) * Ez + h * 64;
#pragma unroll
    for (int dt = 0; dt < 4; ++dt) {
      ushort4 w;
      w.x = f2b(o[dt][0] * inv);
      w.y = f2b(o[dt][1] * inv);
      w.z = f2b(o[dt][2] * inv);
      w.w = f2b(o[dt][3] * inv);
      *(ushort4*)&y[yrow + dt * 16 + l4 * 4] = w;
    }
  }
}

// ---------------- LayerNorm (bf16 in -> bf16 out) ----------------
__global__ __launch_bounds__(256) void ln_bf16(
    const ushort_t* __restrict__ x, const float* __restrict__ w,
    const float* __restrict__ b, ushort_t* __restrict__ out)
{
  __shared__ float red[8];
  const int row = blockIdx.x, tid = threadIdx.x;
  ushort4 xv = *(const ushort4*)&x[(size_t)row * Ez + tid * 4];
  float v0 = b2f(xv.x), v1 = b2f(xv.y), v2 = b2f(xv.z), v3 = b2f(xv.w);
  float s = v0 + v1 + v2 + v3;
  float sq = v0 * v0 + v1 * v1 + v2 * v2 + v3 * v3;
#pragma unroll
  for (int off = 1; off < 64; off <<= 1) { s += __shfl_xor(s, off); sq += __shfl_xor(sq, off); }
  if ((tid & 63) == 0) { red[(tid >> 6) * 2] = s; red[(tid >> 6) * 2 + 1] = sq; }
  __syncthreads();
  const float ts = red[0] + red[2] + red[4] + red[6];
  const float tq = red[1] + red[3] + red[5] + red[7];
  const float mean = ts * (1.f / Ez);
  const float var = tq * (1.f / Ez) - mean * mean;
  const float rstd = rsqrtf(var + 1e-5f);
  float4 wv = *(const float4*)&w[tid * 4];
  float4 bv = *(const float4*)&b[tid * 4];
  ushort4 ov;
  ov.x = f2b((v0 - mean) * rstd * wv.x + bv.x);
  ov.y = f2b((v1 - mean) * rstd * wv.y + bv.y);
  ov.z = f2b((v2 - mean) * rstd * wv.z + bv.z);
  ov.w = f2b((v3 - mean) * rstd * wv.w + bv.w);
  *(ushort4*)&out[(size_t)row * Ez + tid * 4] = ov;
}

// ---------------- misc ----------------
__global__ __launch_bounds__(256) void embed_k(
    const int* __restrict__ idx, const float* __restrict__ wte, ushort_t* __restrict__ x)
{
  int i = blockIdx.x * 256 + threadIdx.x;
  int row = i >> 8, c = (i & 255) << 2;
  float4 v = *(const float4*)&wte[(size_t)idx[row] * Ez + c];
  ushort4 o;
  o.x = f2b(v.x); o.y = f2b(v.y); o.z = f2b(v.z); o.w = f2b(v.w);
  *(ushort4*)&x[(size_t)row * Ez + c] = o;
}

__global__ __launch_bounds__(256) void cvt_bf16(
    const float* __restrict__ in, ushort_t* __restrict__ out, int n)
{
  int i = (blockIdx.x * 256 + threadIdx.x) * 4;
  if (i >= n) return;
  float4 v = *(const float4*)&in[i];
  ushort4 o;
  o.x = f2b(v.x); o.y = f2b(v.y); o.z = f2b(v.z); o.w = f2b(v.w);
  *(ushort4*)&out[i] = o;
}

__global__ __launch_bounds__(256) void cvt_layer(
    const float* __restrict__ Wq, const float* __restrict__ Wk,
    const float* __restrict__ Wv, const float* __restrict__ Wo_,
    const float* __restrict__ Wfc_, const float* __restrict__ Wpj_,
    ushort_t* __restrict__ wqkv, ushort_t* __restrict__ wo,
    ushort_t* __restrict__ wfc, ushort_t* __restrict__ wpj)
{
  int i = (blockIdx.x * 256 + threadIdx.x) * 4;
  const float* src; ushort_t* dst; int off;
  if (i < 1048576)       { src = Wq;   dst = wqkv;           off = i; }
  else if (i < 1310720)  { src = Wk;   dst = wqkv + 1048576; off = i - 1048576; }
  else if (i < 1572864)  { src = Wv;   dst = wqkv + 1310720; off = i - 1310720; }
  else if (i < 2621440)  { src = Wo_;  dst = wo;             off = i - 1572864; }
  else if (i < 6815744)  { src = Wfc_; dst = wfc;            off = i - 2621440; }
  else                   { src = Wpj_; dst = wpj;            off = i - 6815744; }
  float4 v = *(const float4*)&src[off];
  ushort4 o;
  o.x = f2b(v.x); o.y = f2b(v.y); o.z = f2b(v.z); o.w = f2b(v.w);
  *(ushort4*)&dst[off] = o;
}

// setup: rope table (32768 items) + fused qkv bias (9216 items), one dispatch
__global__ __launch_bounds__(256) void setup_k(
    const float* __restrict__ bq, const float* __restrict__ bk,
    const float* __restrict__ bv, float2* __restrict__ tab, float* __restrict__ qbia)
{
  int i = blockIdx.x * 256 + threadIdx.x;   // Tz*32 = 32768
  int t = i >> 5, j = i & 31;
  float theta = powf(10000.0f, -(float)j / 32.0f);
  float ang = (float)(t + 1) * theta;
  tab[i] = make_float2(cosf(ang), sinf(ang));
  if (i < Lz * QKVz) {
    int l = i / QKVz, jj = i - l * QKVz;
    float v = (jj < Ez) ? bq[l * Ez + jj]
            : ((jj < Ez + EKVz) ? bk[l * EKVz + jj - Ez] : bv[l * EKVz + jj - Ez - EKVz]);
    qbia[i] = v;
  }
}

// ---------------- launchers ----------------
template<int BIAS, int RES, int GELU, int WBF16, int ROPE = 0>
static void launch_gemm64(const ushort_t* A, const ushort_t* Bw, const float* bias,
                          const ushort_t* res, ushort_t* Cb,
                          ushort_t* vtb, const float* tab,
                          int M, int N, int K, hipStream_t s)
{
  dim3 g(M / 128, N / 64);
  gemm_bt64<BIAS, RES, GELU, WBF16, ROPE><<<g, 256, 0, s>>>(
      A, Bw, bias, res, Cb, vtb, (const float2*)tab, M, N, K);
}

extern "C" void kernel_launch(void* const* d_in, const int* in_sizes, int n_in,
                              void* d_out, int out_size, void* d_ws, size_t ws_size,
                              hipStream_t stream)
{
  (void)in_sizes; (void)n_in; (void)out_size; (void)ws_size;
  const int*   idx   = (const int*)d_in[0];
  const float* wte   = (const float*)d_in[1];
  const float* Wq    = (const float*)d_in[2];
  const float* bq    = (const float*)d_in[3];
  const float* Wk    = (const float*)d_in[4];
  const float* bk    = (const float*)d_in[5];
  const float* Wv    = (const float*)d_in[6];
  const float* bv    = (const float*)d_in[7];
  const float* Wo    = (const float*)d_in[8];
  const float* bo    = (const float*)d_in[9];
  const float* ln1w  = (const float*)d_in[10];
  const float* ln1b  = (const float*)d_in[11];
  const float* ln2w  = (const float*)d_in[12];
  const float* ln2b  = (const float*)d_in[13];
  const float* Wfc   = (const float*)d_in[14];
  const float* bfc   = (const float*)d_in[15];
  const float* Wproj = (const float*)d_in[16];
  const float* bproj = (const float*)d_in[17];
  const float* lnfw  = (const float*)d_in[18];
  const float* lnfb  = (const float*)d_in[19];
  const float* lmh   = (const float*)d_in[20];
  float* out = (float*)d_out;

  char* ws = (char*)d_ws;
  size_t off = 0;
  auto alloc = [&](size_t bytes) -> void* {
    void* p = ws + off;
    off += (bytes + 255) & ~(size_t)255;
    return p;
  };
  ushort_t* wbuf  = (ushort_t*)alloc((size_t)Vz * Ez * 2);
  ushort_t* x     = (ushort_t*)alloc((size_t)Bz * Tz * Ez * 2);
  ushort_t* hb    = (ushort_t*)alloc((size_t)Bz * Tz * Ez * 2);
  ushort_t* qkvb  = (ushort_t*)alloc((size_t)Bz * Tz * QKVz * 2);
  ushort_t* vtb   = (ushort_t*)alloc((size_t)Bz * HKVz * 64 * Tz * 2);
  ushort_t* yb    = (ushort_t*)alloc((size_t)Bz * Tz * Ez * 2);
  ushort_t* ffb   = (ushort_t*)alloc((size_t)Bz * Tz * FFz * 2);
  float*    tab   = (float*)alloc((size_t)Tz * 32 * 2 * 4);
  float*    qbia  = (float*)alloc((size_t)Lz * QKVz * 4);

  ushort_t* wqkv = wbuf;
  ushort_t* wo   = wqkv + (size_t)QKVz * Ez;
  ushort_t* wfc  = wo + (size_t)Ez * Ez;
  ushort_t* wpj  = wfc + (size_t)FFz * Ez;

  const int M = Bz * Tz;

  setup_k<<<Tz * 32 / 256, 256, 0, stream>>>(bq, bk, bv, (float2*)tab, qbia);
  embed_k<<<Bz * Tz, 256, 0, stream>>>(idx, wte, x);

  for (int l = 0; l < Lz; ++l) {
    ln_bf16<<<M, 256, 0, stream>>>(x, ln1w + l * Ez, ln1b + l * Ez, hb);
    cvt_layer<<<10752, 256, 0, stream>>>(
        Wq + (size_t)l * Ez * Ez, Wk + (size_t)l * EKVz * Ez, Wv + (size_t)l * EKVz * Ez,
        Wo + (size_t)l * Ez * Ez, Wfc + (size_t)l * FFz * Ez, Wproj + (size_t)l * Ez * FFz,
        wqkv, wo, wfc, wpj);
    // QKV + fused RoPE + fused V-transpose (768 blocks = 3/CU)
    launch_gemm64<1, 0, 0, 1, 1>(hb, wqkv, qbia + l * QKVz, nullptr, qkvb, vtb, tab,
                                 M, QKVz, Ez, stream);
    attn_k<<<dim3(Tz / 128, Bz * HQz), 256, 0, stream>>>(qkvb, vtb, yb);
    // Wo + bf16 residual add -> x
    launch_gemm64<1, 1, 0, 1>(yb, wo, bo + l * Ez, x, x, nullptr, nullptr,
                              M, Ez, Ez, stream);
    ln_bf16<<<M, 256, 0, stream>>>(x, ln2w + l * Ez, ln2b + l * Ez, hb);
    // FC + GELU on bt256 (traffic-optimal for N=4096)
    {
      dim3 g(M / 256, FFz / 256);
      gemm_bt256<1, 1, 0><<<g, 512, 0, stream>>>(hb, wfc, bfc + l * FFz, nullptr, ffb, M, FFz, Ez);
    }
    // proj + bf16 residual add -> x
    launch_gemm64<1, 1, 0, 1>(ffb, wpj, bproj + l * Ez, x, x, nullptr, nullptr,
                              M, Ez, FFz, stream);
  }
  ln_bf16<<<M, 256, 0, stream>>>(x, lnfw, lnfb, hb);
  cvt_bf16<<<(Vz * Ez / 4 + 255) / 256, 256, 0, stream>>>(lmh, wbuf, Vz * Ez);
  {
    dim3 g(M / 256, Vz / 256);
    gemm_bt256<0, 0, 1><<<g, 512, 0, stream>>>(hb, wbuf, nullptr, out, nullptr, M, Vz, Ez);
  }
}